// Round 6
// baseline (433.609 us; speedup 1.0000x reference)
//
#include <hip/hip_runtime.h>

typedef unsigned short u16;
typedef unsigned int   u32;
typedef __attribute__((ext_vector_type(8))) short short8;  // 8 bf16 = one MFMA A/B frag
typedef __attribute__((ext_vector_type(4))) float f32x4;   // MFMA C/D frag

__device__ __forceinline__ u16 f2bf(float f) {
  u32 u = __float_as_uint(f);
  u32 r = u + 0x7fffu + ((u >> 16) & 1u);
  return (u16)(r >> 16);
}

__device__ __forceinline__ void gl_lds16(const u16* g, u16* l) {
  __builtin_amdgcn_global_load_lds(
      (const __attribute__((address_space(1))) u32*)g,
      (__attribute__((address_space(3))) u32*)l, 16, 0, 0);
}

// ---------------------------------------------------------------------------
// Kernel 1: fold q/k projections into the input convs; emit bf16 Wqkb.
// ---------------------------------------------------------------------------
__global__ __launch_bounds__(256) void k_combine_qk(
    const float* __restrict__ wt, const float* __restrict__ bt,
    const float* __restrict__ wb, const float* __restrict__ bb,
    const float* __restrict__ s_w1, const float* __restrict__ s_b1,
    const float* __restrict__ s_w2, const float* __restrict__ s_b2,
    const float* __restrict__ c_wq, const float* __restrict__ c_bq,
    const float* __restrict__ c_wk, const float* __restrict__ c_bk,
    u16* __restrict__ Wqkb, float* __restrict__ bqk) {
  int j = blockIdx.x;            // 0..255
  int g = j >> 6, r = j & 63;
  const float* sw; const float* sb;
  if (g == 0)      { sw = s_w1; sb = s_b1; }
  else if (g == 1) { sw = s_w2; sb = s_b2; }
  else if (g == 2) { sw = c_wq; sb = c_bq; }
  else             { sw = c_wk; sb = c_bk; }
  int cbase = (g < 2) ? 0 : 256;

  __shared__ float swr[256];
  __shared__ float red[256];
  int t = threadIdx.x;
  swr[t] = sw[r * 256 + t];
  __syncthreads();

  float a0 = 0.f, a1 = 0.f, a2 = 0.f, a3 = 0.f;
#pragma unroll 4
  for (int c = 0; c < 256; ++c) {
    float a = swr[c];
    int row = (cbase + c) * 512;
    a0 += a * wt[row + t];
    a1 += a * wt[row + 256 + t];
    a2 += a * wb[row + t];
    a3 += a * wb[row + 256 + t];
  }
  Wqkb[j * 1024 + t]       = f2bf(a0);
  Wqkb[j * 1024 + 256 + t] = f2bf(a1);
  Wqkb[j * 1024 + 512 + t] = f2bf(a2);
  Wqkb[j * 1024 + 768 + t] = f2bf(a3);

  red[t] = swr[t] * (bt[cbase + t] + bb[cbase + t]);
  __syncthreads();
  for (int s = 128; s > 0; s >>= 1) {
    if (t < s) red[t] += red[t + s];
    __syncthreads();
  }
  if (t == 0) bqk[j] = red[0] + sb[r];
}

// ---------------------------------------------------------------------------
// Kernel 2: fold s_wo / c_wo into the final conv; emit bf16 Wfb.
// ---------------------------------------------------------------------------
__global__ __launch_bounds__(128) void k_combine_f(
    const float* __restrict__ f_w, const float* __restrict__ f_b,
    const float* __restrict__ s_wo, const float* __restrict__ s_bo,
    const float* __restrict__ c_wo, const float* __restrict__ c_bo,
    u16* __restrict__ Wfb, float* __restrict__ bfb) {
  int o = blockIdx.x;   // 0..511
  int t = threadIdx.x;  // 0..127
  __shared__ float fwr[512];
  __shared__ float red[128];
  for (int i = t; i < 512; i += 128) fwr[i] = f_w[o * 512 + i];
  __syncthreads();

  float acc = 0.f;
  if (t < 64) {
#pragma unroll 4
    for (int c = 0; c < 256; ++c) acc += fwr[c] * s_wo[c * 64 + t];
  } else {
    int rr = t - 64;
#pragma unroll 4
    for (int c = 0; c < 256; ++c) acc += fwr[256 + c] * c_wo[c * 64 + rr];
  }
  Wfb[o * 128 + t] = f2bf(acc);

  red[t] = fwr[t] * s_bo[t] + fwr[t + 128] * s_bo[t + 128]
         + fwr[256 + t] * c_bo[t] + fwr[384 + t] * c_bo[t + 128];
  __syncthreads();
  for (int s = 64; s > 0; s >>= 1) {
    if (t < s) red[t] += red[t + s];
    __syncthreads();
  }
  if (t == 0) bfb[o] = red[0] + f_b[o];
}

// ---------------------------------------------------------------------------
// Kernel 3 (MFMA, v6): qk[b][j][n] = sum_k Wqk[j][k]*x[b][k][n] + bqk[j]
// M=256, K=1024, N=4096/batch. 128x128 tile, BK=32, 32 K-iters.
// v6 = v5 counted-vmcnt pipeline + FLOAT4 X LOADS: thread owns a 4n x 4k
// micro-block -> 4 global_load_dwordx4 per phase (was 16 scalar dwords).
// writeX emits the IDENTICAL LDS image as v5 (same f2bf values, same swizzled
// positions) -> MFMA inputs bit-identical. vmcnt count 16 -> 4.
// LDS = 2*8KB(A) + 2*8KB(X) = 32 KB.
// ---------------------------------------------------------------------------
__global__ __launch_bounds__(256) void k_gemm_qk_mfma(
    const float* __restrict__ top, const float* __restrict__ bot,
    const u16* __restrict__ Wqkb, const float* __restrict__ bqk,
    float* __restrict__ qk) {
  int b = blockIdx.z, j0 = blockIdx.y * 128, n0 = blockIdx.x * 128;
  __shared__ __align__(16) u16 Aj[2][128][32];
  __shared__ __align__(16) u16 Xs[2][128][32];
  int t = threadIdx.x;
  int wv = t >> 6, lane = t & 63;
  int wr = wv >> 1, wc = wv & 1;
  int q = lane >> 4, l = lane & 15;

  f32x4 acc[4][4];
#pragma unroll
  for (int tr = 0; tr < 4; ++tr)
#pragma unroll
    for (int tc = 0; tc < 4; ++tc) acc[tr][tc] = (f32x4){0.f, 0.f, 0.f, 0.f};

  // ---- X staging: thread owns n in [4a,4a+3], k in [4xs,4xs+3] ------------
  int a = t & 31;                                // n-group
  int xs = t >> 5;                               // k-group 0..7
  // ---- A staging (gl_lds, lane-linear dest): per-lane swizzled source -----
  int asr4 = lane >> 2;                          // row within 16-row chunk
  int asc = (lane & 3) ^ ((asr4 + (asr4 >> 2)) & 3);  // logical 16B chunk to fetch
  // ---- fragment-read swizzled chunk offsets (per-thread constants) --------
  int rowA = wr * 64 + l;
  int rowX = wc * 64 + l;
  int fswA = (q ^ ((rowA + (rowA >> 2)) & 3)) << 4;
  int fswX = (q ^ ((rowX + (rowX >> 2)) & 3)) << 4;

  f32x4 xva[4], xvb[4];

  auto stageA = [&](int kc, u16* dst) {
#pragma unroll
    for (int pp = 0; pp < 2; ++pp) {
      int p = wv * 2 + pp;                       // 1KB chunk 0..7
      int row = p * 16 + asr4;                   // 0..127
      gl_lds16(Wqkb + (size_t)(j0 + row) * 1024 + kc + asc * 8, dst + p * 512);
    }
  };
  auto loadX = [&](int kc, f32x4 (&xv)[4]) {
    const float* src = (kc < 512) ? top : bot;
    int c0 = kc & 511;
    const float* xb = src + (size_t)(b * 512 + c0) * 4096 + n0 + 4 * a;
#pragma unroll
    for (int d = 0; d < 4; ++d)
      xv[d] = *reinterpret_cast<const f32x4*>(&xb[(size_t)(4 * xs + d) * 4096]);
  };
  auto writeX = [&](f32x4 (&xv)[4], u16* dst) {
    char* base = reinterpret_cast<char*>(dst);
#pragma unroll
    for (int i = 0; i < 4; ++i) {
      int n = 4 * a + i;
      int key = (n + (n >> 2)) & 3;
      int col = ((((xs >> 1) ^ key) << 4) | ((xs & 1) << 3));
      uint2 pk;
      pk.x = (u32)f2bf(xv[0][i]) | ((u32)f2bf(xv[1][i]) << 16);
      pk.y = (u32)f2bf(xv[2][i]) | ((u32)f2bf(xv[3][i]) << 16);
      *reinterpret_cast<uint2*>(base + n * 64 + col) = pk;
    }
  };
  auto compute = [&](int bufsel) {
    const char* Ab = reinterpret_cast<const char*>(&Aj[bufsel][0][0]);
    const char* Xb = reinterpret_cast<const char*>(&Xs[bufsel][0][0]);
    short8 af[4], bfr[4];
#pragma unroll
    for (int tr = 0; tr < 4; ++tr)
      af[tr] = *reinterpret_cast<const short8*>(Ab + (rowA + tr * 16) * 64 + fswA);
#pragma unroll
    for (int tc = 0; tc < 4; ++tc)
      bfr[tc] = *reinterpret_cast<const short8*>(Xb + (rowX + tc * 16) * 64 + fswX);
#pragma unroll
    for (int tr = 0; tr < 4; ++tr)
#pragma unroll
      for (int tc = 0; tc < 4; ++tc)
        acc[tr][tc] = __builtin_amdgcn_mfma_f32_16x16x32_bf16(
            af[tr], bfr[tc], acc[tr][tc], 0, 0, 0);
  };

  // ---- prologue: tile 0 resident; tile 1 X-data in flight -----------------
  stageA(0, &Aj[0][0][0]);
  loadX(0, xva);
  writeX(xva, &Xs[0][0][0]);     // register deps drain vmcnt (A0 done too)
  loadX(32, xvb);                // 4 in flight across the barrier
  asm volatile("s_waitcnt lgkmcnt(0)" ::: "memory");
  __builtin_amdgcn_s_barrier();

  // ---- main loop: phases 0..29 (two per trip) -----------------------------
  for (int it2 = 0; it2 < 15; ++it2) {
    int e = it2 * 2;
    // phase e (buf 0): prep tile e+1 in buf1, load tile e+2
    stageA((e + 1) * 32, &Aj[1][0][0]);
    loadX((e + 2) * 32, xva);
    writeX(xvb, &Xs[1][0][0]);   // waits tile-(e+1) loads (aged 1 phase)
    compute(0);
    asm volatile("s_waitcnt vmcnt(4) lgkmcnt(0)" ::: "memory");
    __builtin_amdgcn_s_barrier();
    // phase e+1 (buf 1): prep tile e+2 in buf0, load tile e+3
    stageA((e + 2) * 32, &Aj[0][0][0]);
    loadX((e + 3) * 32, xvb);
    writeX(xva, &Xs[0][0][0]);
    compute(1);
    asm volatile("s_waitcnt vmcnt(4) lgkmcnt(0)" ::: "memory");
    __builtin_amdgcn_s_barrier();
  }
  // ---- peel: phase 30 (prepare tile 31), phase 31 -------------------------
  stageA(31 * 32, &Aj[1][0][0]);
  writeX(xvb, &Xs[1][0][0]);     // xvb: tile 31 (loaded phase 29)
  compute(0);
  asm volatile("s_waitcnt vmcnt(0) lgkmcnt(0)" ::: "memory");
  __builtin_amdgcn_s_barrier();
  compute(1);

  // ---- epilogue -----------------------------------------------------------
#pragma unroll
  for (int tr = 0; tr < 4; ++tr) {
    int j = j0 + wr * 64 + tr * 16 + q * 4;
    float4 bias = *reinterpret_cast<const float4*>(&bqk[j]);
#pragma unroll
    for (int tc = 0; tc < 4; ++tc) {
      int n = n0 + wc * 64 + tc * 16 + l;
      float* dst = qk + (size_t)(b * 256 + j) * 4096 + n;
      dst[0]        = acc[tr][tc][0] + bias.x;
      dst[4096]     = acc[tr][tc][1] + bias.y;
      dst[2 * 4096] = acc[tr][tc][2] + bias.z;
      dst[3 * 4096] = acc[tr][tc][3] + bias.w;
    }
  }
}

// ---------------------------------------------------------------------------
// Kernel T1 (v2): channel-minor bf16 copies of q1,k1 — no LDS, all dwordx4.
// Thread owns 4 n (n=4a..4a+3) x 8 j (j=8c..8c+7): 8 dwordx4 loads,
// 32 f2bf, 4 dwordx4 stores. Same values/locations as v1 -> bit-identical.
// ---------------------------------------------------------------------------
__global__ __launch_bounds__(256) void k_transpose_qk(
    const float* __restrict__ qk, u16* __restrict__ q1t, u16* __restrict__ k1t) {
  int b = blockIdx.y, n0 = blockIdx.x * 64;
  int t = threadIdx.x;
  int a = t & 15;                  // n-group: n = 4a..4a+3
  int c = t >> 4;                  // j-chunk: c<8 -> q1 rows, c>=8 -> k1 rows
  int jb = 8 * (c & 7);            // j base within the 64-row half
  const float* src =
      qk + ((size_t)(b * 256) + (c >> 3) * 64 + jb) * 4096 + n0 + 4 * a;
  f32x4 v[8];
#pragma unroll
  for (int i = 0; i < 8; ++i)
    v[i] = *reinterpret_cast<const f32x4*>(&src[(size_t)i * 4096]);
  u16* dstbase = (c < 8) ? q1t : k1t;
#pragma unroll
  for (int i = 0; i < 4; ++i) {    // n = n0 + 4a + i
    int n = n0 + 4 * a + i;
    u32 pk[4];
#pragma unroll
    for (int kk = 0; kk < 4; ++kk)
      pk[kk] = (u32)f2bf(v[2 * kk][i]) | ((u32)f2bf(v[2 * kk + 1][i]) << 16);
    *reinterpret_cast<uint4*>(dstbase + ((size_t)(b * 4096) + n) * 64 + jb) =
        *reinterpret_cast<const uint4*>(pk);
  }
}

// ---------------------------------------------------------------------------
// Kernel 4 (MFMA, v2): spatial softmax denominators + fused k1d scaling.
// ---------------------------------------------------------------------------
__global__ __launch_bounds__(256) void k_sp_stats_mfma(
    const u16* __restrict__ q1t, const u16* __restrict__ k1t,
    const float* __restrict__ qk, u16* __restrict__ k1d) {
  int b = blockIdx.y, n0 = blockIdx.x * 64;
  __shared__ u16 Qs[64][72];
  __shared__ float red[4][64][16];
  __shared__ float dvs[64];
  int t = threadIdx.x;
  int wv = t >> 6, lane = t & 63;
  int q = lane >> 4, l = lane & 15;

  {
    const u32* src = reinterpret_cast<const u32*>(q1t + ((size_t)(b * 4096) + n0) * 64);
    for (int i = t; i < 2048; i += 256) {
      int n = i >> 5, c = i & 31;
      reinterpret_cast<u32*>(&Qs[n][0])[c] = src[n * 32 + c];
    }
  }
  __syncthreads();

  short8 afr[4][2];
#pragma unroll
  for (int tn = 0; tn < 4; ++tn)
#pragma unroll
    for (int kh = 0; kh < 2; ++kh)
      afr[tn][kh] = *reinterpret_cast<const short8*>(&Qs[tn * 16 + l][kh * 32 + q * 8]);

  const u16* kbase = k1t + (size_t)b * 4096 * 64;
  float dsum[4][4];
#pragma unroll
  for (int tn = 0; tn < 4; ++tn)
#pragma unroll
    for (int i = 0; i < 4; ++i) dsum[tn][i] = 0.f;

  for (int mt = wv; mt < 64; mt += 4) {
    int m0 = mt * 64;
#pragma unroll
    for (int tm = 0; tm < 4; ++tm) {
      const u16* kp = kbase + ((size_t)(m0 + tm * 16 + l)) * 64;
      short8 b0 = *reinterpret_cast<const short8*>(kp + q * 8);
      short8 b1 = *reinterpret_cast<const short8*>(kp + 32 + q * 8);
#pragma unroll
      for (int tn = 0; tn < 4; ++tn) {
        f32x4 acc = {0.f, 0.f, 0.f, 0.f};
        acc = __builtin_amdgcn_mfma_f32_16x16x32_bf16(afr[tn][0], b0, acc, 0, 0, 0);
        acc = __builtin_amdgcn_mfma_f32_16x16x32_bf16(afr[tn][1], b1, acc, 0, 0, 0);
#pragma unroll
        for (int i = 0; i < 4; ++i) dsum[tn][i] += __expf(acc[i]);
      }
    }
  }

#pragma unroll
  for (int tn = 0; tn < 4; ++tn)
#pragma unroll
    for (int i = 0; i < 4; ++i)
      red[wv][tn * 16 + q * 4 + i][l] = dsum[tn][i];
  __syncthreads();
  if (t < 64) {
    float s = 0.f;
#pragma unroll
    for (int v = 0; v < 4; ++v)
#pragma unroll
      for (int u = 0; u < 16; ++u) s += red[v][t][u];
    dvs[t] = 1.0f / s;
  }
  __syncthreads();

  // fused: k1d for this n-slice (identical numerics to old k_scale_k1d)
  const float* k1src = qk + ((size_t)(b * 256) + 64) * 4096 + n0;
  u16* kdst = k1d + (size_t)(b * 64) * 4096 + n0;
  for (int i = t; i < 4096; i += 256) {
    int r = i >> 6, n = i & 63;
    kdst[(size_t)r * 4096 + n] = f2bf(k1src[(size_t)r * 4096 + n] * dvs[n]);
  }
}

// ---------------------------------------------------------------------------
// Kernel 8 (MFMA, v2): spatial apply. (unchanged)
// ---------------------------------------------------------------------------
#define NSPLIT 2

__device__ __forceinline__ void stage_qk(const u16* qb, const u16* kb, int noff,
                                         u16* qdst, u16* kdst,
                                         int wv, int rsub, int scol) {
#pragma unroll
  for (int pp = 0; pp < 2; ++pp) {
    int p = wv * 2 + pp;                 // 1KB chunk index 0..7 (2 per wave)
    int row = p * 8 + rsub;              // tile row 0..63
    gl_lds16(qb + ((size_t)(noff + row)) * 64 + scol * 8, qdst + p * 512);
    gl_lds16(kb + (size_t)row * 4096 + noff + scol * 8, kdst + p * 512);
  }
}

__global__ __launch_bounds__(256) void k_sp_apply_mfma(
    const u16* __restrict__ q1t, const u16* __restrict__ k1t,
    const u16* __restrict__ k1d, float* __restrict__ spre) {
  int b = blockIdx.z, m0 = blockIdx.x * 64;
  int n_base = blockIdx.y * (4096 / NSPLIT);
  const int NT = 64 / NSPLIT;

  __shared__ __align__(16) u16 Qs[2][64][64];
  __shared__ __align__(16) u16 Ks[2][64][64];
  __shared__ __align__(16) u16 Wt[64][64];

  int t = threadIdx.x;
  int wv = t >> 6, lane = t & 63;
  int q = lane >> 4, l = lane & 15;
  int sw = l & 7;                        // swizzle key: row&7 == l&7 for frag rows
  int rsub = lane >> 3;                  // staging: row within 8-row chunk
  int scol = (lane & 7) ^ rsub;          // staging: pre-swizzled source 16B-chunk

  // B fragments (K^T tile at m0): straight global->reg, live whole kernel.
  const u16* ktp = k1t + ((size_t)(b * 4096) + m0 + wv * 16 + l) * 64;
  short8 bS0 = *reinterpret_cast<const short8*>(ktp + q * 8);
  short8 bS1 = *reinterpret_cast<const short8*>(ktp + 32 + q * 8);

  const u16* qb = q1t + (size_t)b * 4096 * 64;
  const u16* kb = k1d + (size_t)b * 64 * 4096;

  f32x4 accO[4];
#pragma unroll
  for (int tr = 0; tr < 4; ++tr) accO[tr] = (f32x4){0.f, 0.f, 0.f, 0.f};

  stage_qk(qb, kb, n_base, &Qs[0][0][0], &Ks[0][0][0], wv, rsub, scol);
  __syncthreads();   // vmcnt(0) drain: buf0 ready

  int wrow = wv * 16 + l;
  char* wp = reinterpret_cast<char*>(&Wt[wrow][0]);
  int c_a0 = (q ^ sw) << 4;              // swizzled byte offset of chunk q
  int c_a1 = c_a0 ^ 64;                  // chunk q+4

  int cur = 0;
  for (int nt = 0; nt < NT; ++nt) {
    if (nt + 1 < NT)
      stage_qk(qb, kb, n_base + (nt + 1) * 64,
               &Qs[cur ^ 1][0][0], &Ks[cur ^ 1][0][0], wv, rsub, scol);

    const u16(*Qc)[64] = Qs[cur];
    const u16(*Kc)[64] = Ks[cur];

    // scores tile: W[n][m] = exp(q1[n] . k1[m]) ; wave-private Wt round-trip
#pragma unroll
    for (int tn = 0; tn < 4; ++tn) {
      const char* qrow = reinterpret_cast<const char*>(&Qc[tn * 16 + l][0]);
      short8 a0 = *reinterpret_cast<const short8*>(qrow + c_a0);
      short8 a1 = *reinterpret_cast<const short8*>(qrow + c_a1);
      f32x4 s = {0.f, 0.f, 0.f, 0.f};
      s = __builtin_amdgcn_mfma_f32_16x16x32_bf16(a0, bS0, s, 0, 0, 0);
      s = __builtin_amdgcn_mfma_f32_16x16x32_bf16(a1, bS1, s, 0, 0, 0);
      u16 w0 = f2bf(__expf(s[0]));
      u16 w1 = f2bf(__expf(s[1]));
      u16 w2 = f2bf(__expf(s[2]));
      u16 w3 = f2bf(__expf(s[3]));
      uint2 pk;
      pk.x = (u32)w0 | ((u32)w1 << 16);
      pk.y = (u32)w2 | ((u32)w3 << 16);
      *reinterpret_cast<uint2*>(
          wp + ((((tn * 2 + (q >> 1)) ^ sw) << 4) | ((q & 1) << 3))) = pk;
    }

    short8 bW0 = *reinterpret_cast<const short8*>(wp + c_a0);
    short8 bW1 = *reinterpret_cast<const short8*>(wp + c_a1);
#pragma unroll
    for (int tr = 0; tr < 4; ++tr) {
      const char* krow = reinterpret_cast<const char*>(&Kc[tr * 16 + l][0]);
      short8 a0 = *reinterpret_cast<const short8*>(krow + c_a0);
      short8 a1 = *reinterpret_cast<const short8*>(krow + c_a1);
      accO[tr] = __builtin_amdgcn_mfma_f32_16x16x32_bf16(a0, bW0, accO[tr], 0, 0, 0);
      accO[tr] = __builtin_amdgcn_mfma_f32_16x16x32_bf16(a1, bW1, accO[tr], 0, 0, 0);
    }

    __syncthreads();   // drains vmcnt (next buf ready) + lgkmcnt (cur reads done)
    cur ^= 1;
  }

#pragma unroll
  for (int tr = 0; tr < 4; ++tr)
#pragma unroll
    for (int i = 0; i < 4; ++i)
      atomicAdd(&spre[(size_t)(b * 64 + tr * 16 + q * 4 + i) * 4096 + m0 + wrow],
                accO[tr][i]);
}

// ---------------------------------------------------------------------------
// Kernel 5 (v2): channel attention partial scores. 32 n-chunks -> 256 blocks.
// ---------------------------------------------------------------------------
__global__ __launch_bounds__(256) void k_ch_scores(
    const float* __restrict__ qk, float* __restrict__ part) {
  int b = blockIdx.y, ch = blockIdx.x;   // ch 0..31, chunk of 128 n
  const float* q2 = qk + (size_t)(b * 256 + 128) * 4096;
  const float* k2 = qk + (size_t)(b * 256 + 192) * 4096;
  __shared__ float Qs[64][65];
  __shared__ float Ks[64][65];
  int t = threadIdx.x, ti = t >> 4, tj = t & 15;
  float acc[4][4] = {};

  for (int sub = 0; sub < 2; ++sub) {
    int n0 = ch * 128 + sub * 64;
    __syncthreads();
    for (int i = t; i < 4096; i += 256) {
      int r = i >> 6, n = i & 63;
      Qs[r][n] = q2[(size_t)r * 4096 + n0 + n];
      Ks[r][n] = k2[(size_t)r * 4096 + n0 + n];
    }
    __syncthreads();
#pragma unroll
    for (int n = 0; n < 64; ++n) {
      float qa[4], ka[4];
#pragma unroll
      for (int i = 0; i < 4; ++i) qa[i] = Qs[ti * 4 + i][n];
#pragma unroll
      for (int jx = 0; jx < 4; ++jx) ka[jx] = Ks[tj * 4 + jx][n];
#pragma unroll
      for (int i = 0; i < 4; ++i)
#pragma unroll
        for (int jx = 0; jx < 4; ++jx) acc[i][jx] += qa[i] * ka[jx];
    }
  }
#pragma unroll
  for (int i = 0; i < 4; ++i)
#pragma unroll
    for (int jx = 0; jx < 4; ++jx)
      part[(size_t)(b * 32 + ch) * 4096 + (ti * 4 + i) * 64 + tj * 4 + jx] = acc[i][jx];
}

// ---------------------------------------------------------------------------
// Kernel 6 (v2): reduce 32 partials + row softmax -> attn2[b][r][s]
// ---------------------------------------------------------------------------
__global__ __launch_bounds__(64) void k_ch_softmax(
    const float* __restrict__ part, float* __restrict__ attn2) {
  int bid = blockIdx.x;          // 512 = 8 b * 64 r
  int b = bid >> 6, r = bid & 63;
  int s = threadIdx.x;
  const float* p0 = part + (size_t)(b * 32) * 4096 + r * 64 + s;
  float sum = 0.f;
#pragma unroll
  for (int c = 0; c < 32; ++c) sum += p0[(size_t)c * 4096];
  float mx = sum;
#pragma unroll
  for (int o = 32; o > 0; o >>= 1) mx = fmaxf(mx, __shfl_xor(mx, o));
  float e = __expf(sum - mx);
  float den = e;
#pragma unroll
  for (int o = 32; o > 0; o >>= 1) den += __shfl_xor(den, o);
  attn2[(size_t)b * 4096 + r * 64 + s] = e / den;
}

// ---------------------------------------------------------------------------
// Kernel 7 (v2): cpre[b][r][n] = sum_s attn2[r,s] * k2[s,n]
// ---------------------------------------------------------------------------
__global__ __launch_bounds__(256) void k_ch_apply(
    const float* __restrict__ qk, const float* __restrict__ attn2,
    float* __restrict__ cpre) {
  int b = blockIdx.y;
  int t = threadIdx.x;
  int n = blockIdx.x * 64 + (t & 63);
  int qr = t >> 6;                      // r-quarter 0..3
  const float* k2 = qk + (size_t)(b * 256 + 192) * 4096;
  __shared__ float As[64][64];
  {
    float4* As4 = reinterpret_cast<float4*>(&As[0][0]);
    const float4* a4 = reinterpret_cast<const float4*>(attn2 + (size_t)b * 4096);
    for (int i = t; i < 1024; i += 256) As4[i] = a4[i];
  }
  __syncthreads();

  float acc[16];
#pragma unroll
  for (int rr = 0; rr < 16; ++rr) acc[rr] = 0.f;
  for (int s4 = 0; s4 < 64; s4 += 4) {
    float kv0 = k2[(size_t)(s4 + 0) * 4096 + n];
    float kv1 = k2[(size_t)(s4 + 1) * 4096 + n];
    float kv2 = k2[(size_t)(s4 + 2) * 4096 + n];
    float kv3 = k2[(size_t)(s4 + 3) * 4096 + n];
#pragma unroll
    for (int rr = 0; rr < 16; ++rr) {
      float4 w = *reinterpret_cast<const float4*>(&As[qr * 16 + rr][s4]);
      acc[rr] += w.x * kv0 + w.y * kv1 + w.z * kv2 + w.w * kv3;
    }
  }
#pragma unroll
  for (int rr = 0; rr < 16; ++rr)
    cpre[(size_t)(b * 64 + qr * 16 + rr) * 4096 + n] = acc[rr];
}

// ---------------------------------------------------------------------------
// Kernel 9 (MFMA, v2): final fused conv, gemm-v6 template.
// out[b][o][n] = Wf[o][0:64]@spre + Wf[o][64:128]@cpre + bfb[o]
// M=512, K=128, N=4096/batch. 128x128 tile, BK=32, 4 K-iters, counted vmcnt.
// Same MFMA order/values as v1 -> bit-identical.
// ---------------------------------------------------------------------------
__global__ __launch_bounds__(256) void k_final_mfma(
    const float* __restrict__ spre, const float* __restrict__ cpre,
    const u16* __restrict__ Wfb, const float* __restrict__ bfb,
    float* __restrict__ out) {
  int b = blockIdx.z, o0 = blockIdx.y * 128, n0 = blockIdx.x * 128;
  __shared__ __align__(16) u16 Aj[2][128][32];
  __shared__ __align__(16) u16 Xs[2][128][32];
  int t = threadIdx.x;
  int wv = t >> 6, lane = t & 63;
  int wr = wv >> 1, wc = wv & 1;
  int q = lane >> 4, l = lane & 15;

  f32x4 acc[4][4];
#pragma unroll
  for (int tr = 0; tr < 4; ++tr)
#pragma unroll
    for (int tc = 0; tc < 4; ++tc) acc[tr][tc] = (f32x4){0.f, 0.f, 0.f, 0.f};

  int a = t & 31;
  int xs = t >> 5;
  int asr4 = lane >> 2;
  int asc = (lane & 3) ^ ((asr4 + (asr4 >> 2)) & 3);
  int rowA = wr * 64 + l;
  int rowX = wc * 64 + l;
  int fswA = (q ^ ((rowA + (rowA >> 2)) & 3)) << 4;
  int fswX = (q ^ ((rowX + (rowX >> 2)) & 3)) << 4;

  f32x4 xva[4], xvb[4];

  auto stageA = [&](int kc, u16* dst) {
#pragma unroll
    for (int pp = 0; pp < 2; ++pp) {
      int p = wv * 2 + pp;
      int row = p * 16 + asr4;
      gl_lds16(Wfb + (size_t)(o0 + row) * 128 + kc + asc * 8, dst + p * 512);
    }
  };
  auto loadX = [&](int kc, f32x4 (&xv)[4]) {
    const float* src = (kc < 64) ? spre : cpre;
    int r0 = kc & 63;
    const float* xb = src + (size_t)(b * 64 + r0) * 4096 + n0 + 4 * a;
#pragma unroll
    for (int d = 0; d < 4; ++d)
      xv[d] = *reinterpret_cast<const f32x4*>(&xb[(size_t)(4 * xs + d) * 4096]);
  };
  auto writeX = [&](f32x4 (&xv)[4], u16* dst) {
    char* base = reinterpret_cast<char*>(dst);
#pragma unroll
    for (int i = 0; i < 4; ++i) {
      int n = 4 * a + i;
      int key = (n + (n >> 2)) & 3;
      int col = ((((xs >> 1) ^ key) << 4) | ((xs & 1) << 3));
      uint2 pk;
      pk.x = (u32)f2bf(xv[0][i]) | ((u32)f2bf(xv[1][i]) << 16);
      pk.y = (u32)f2bf(xv[2][i]) | ((u32)f2bf(xv[3][i]) << 16);
      *reinterpret_cast<uint2*>(base + n * 64 + col) = pk;
    }
  };
  auto compute = [&](int bufsel) {
    const char* Ab = reinterpret_cast<const char*>(&Aj[bufsel][0][0]);
    const char* Xb = reinterpret_cast<const char*>(&Xs[bufsel][0][0]);
    short8 af[4], bfr[4];
#pragma unroll
    for (int tr = 0; tr < 4; ++tr)
      af[tr] = *reinterpret_cast<const short8*>(Ab + (rowA + tr * 16) * 64 + fswA);
#pragma unroll
    for (int tc = 0; tc < 4; ++tc)
      bfr[tc] = *reinterpret_cast<const short8*>(Xb + (rowX + tc * 16) * 64 + fswX);
#pragma unroll
    for (int tr = 0; tr < 4; ++tr)
#pragma unroll
      for (int tc = 0; tc < 4; ++tc)
        acc[tr][tc] = __builtin_amdgcn_mfma_f32_16x16x32_bf16(
            af[tr], bfr[tc], acc[tr][tc], 0, 0, 0);
  };

  // prologue: tile0 resident, tile1 in flight
  stageA(0, &Aj[0][0][0]);
  loadX(0, xva);
  writeX(xva, &Xs[0][0][0]);
  loadX(32, xvb);
  asm volatile("s_waitcnt lgkmcnt(0)" ::: "memory");
  __builtin_amdgcn_s_barrier();
  // phase 0: compute tile0; prep tile1; load tile2
  stageA(32, &Aj[1][0][0]);
  loadX(64, xva);
  writeX(xvb, &Xs[1][0][0]);
  compute(0);
  asm volatile("s_waitcnt vmcnt(4) lgkmcnt(0)" ::: "memory");
  __builtin_amdgcn_s_barrier();
  // phase 1: compute tile1; prep tile2; load tile3
  stageA(64, &Aj[0][0][0]);
  loadX(96, xvb);
  writeX(xva, &Xs[0][0][0]);
  compute(1);
  asm volatile("s_waitcnt vmcnt(4) lgkmcnt(0)" ::: "memory");
  __builtin_amdgcn_s_barrier();
  // phase 2: compute tile2; prep tile3
  stageA(96, &Aj[1][0][0]);
  writeX(xvb, &Xs[1][0][0]);
  compute(0);
  asm volatile("s_waitcnt vmcnt(0) lgkmcnt(0)" ::: "memory");
  __builtin_amdgcn_s_barrier();
  // phase 3
  compute(1);

#pragma unroll
  for (int tr = 0; tr < 4; ++tr) {
    int o = o0 + wr * 64 + tr * 16 + q * 4;
    float4 bias = *reinterpret_cast<const float4*>(&bfb[o]);
#pragma unroll
    for (int tc = 0; tc < 4; ++tc) {
      int n = n0 + wc * 64 + tc * 16 + l;
      float* dst = out + (size_t)(b * 512 + o) * 4096 + n;
      dst[0]        = acc[tr][tc][0] + bias.x;
      dst[4096]     = acc[tr][tc][1] + bias.y;
      dst[2 * 4096] = acc[tr][tc][2] + bias.z;
      dst[3 * 4096] = acc[tr][tc][3] + bias.w;
    }
  }
}

// ---------------------------------------------------------------------------
extern "C" void kernel_launch(void* const* d_in, const int* in_sizes, int n_in,
                              void* d_out, int out_size, void* d_ws, size_t ws_size,
                              hipStream_t stream) {
  const float* top  = (const float*)d_in[0];
  const float* bot  = (const float*)d_in[1];
  const float* wt   = (const float*)d_in[2];
  const float* bt   = (const float*)d_in[3];
  const float* wb   = (const float*)d_in[4];
  const float* bb   = (const float*)d_in[5];
  const float* s_w1 = (const float*)d_in[6];
  const float* s_b1 = (const float*)d_in[7];
  const float* s_w2 = (const float*)d_in[8];
  const float* s_b2 = (const float*)d_in[9];
  const float* s_wo = (const float*)d_in[10];
  const float* s_bo = (const float*)d_in[11];
  const float* c_wq = (const float*)d_in[12];
  const float* c_bq = (const float*)d_in[13];
  const float* c_wk = (const float*)d_in[14];
  const float* c_bk = (const float*)d_in[15];
  const float* c_wo = (const float*)d_in[16];
  const float* c_bo = (const float*)d_in[17];
  const float* f_w  = (const float*)d_in[18];
  const float* f_b  = (const float*)d_in[19];
  float* out = (float*)d_out;

  // d_out (64 MB) doubles as scratch until k_final_mfma overwrites it:
  //   [0,32MB)  qk fp32 [8][256][4096]
  //   [32,36MB) q1t bf16 [8][4096][64]
  //   [36,40MB) k1t bf16 [8][4096][64]
  //   [40,44MB) k1d bf16 [8][64][4096]
  //   [44,48MB) part fp32 [8][32][64][64]   (consumed by k_ch_softmax)
  char* ob = (char*)d_out;
  float* qk = (float*)ob;
  u16* q1t = (u16*)(ob + 33554432);
  u16* k1t = (u16*)(ob + 37748736);
  u16* k1d = (u16*)(ob + 41943040);
  float* part = (float*)(ob + 46137344);

  char* ws = (char*)d_ws;
  float* attn2 = (float*)(ws + 1179648);    // [8][64][64]        131,072 B
  float* spre  = (float*)(ws + 1310720);    // [8][64][4096]    8,388,608 B
  float* cpre  = (float*)(ws + 9699328);    // [8][64][4096]    8,388,608 B
  u16*   Wqkb  = (u16*)  (ws + 18087936);   // [256][1024] bf16   524,288 B
  float* bqk   = (float*)(ws + 18612224);   // [256]                1,024 B
  u16*   Wfb   = (u16*)  (ws + 18613248);   // [512][128] bf16    131,072 B
  float* bfb   = (float*)(ws + 18744320);   // [512]                2,048 B

  // spre is accumulated with atomicAdd by the NSPLIT partial blocks -> zero it.
  hipMemsetAsync(spre, 0, 8388608, stream);

  k_combine_qk<<<256, 256, 0, stream>>>(wt, bt, wb, bb, s_w1, s_b1, s_w2, s_b2,
                                        c_wq, c_bq, c_wk, c_bk, Wqkb, bqk);
  k_combine_f<<<512, 128, 0, stream>>>(f_w, f_b, s_wo, s_bo, c_wo, c_bo, Wfb, bfb);
  k_gemm_qk_mfma<<<dim3(32, 2, 8), 256, 0, stream>>>(top, bot, Wqkb, bqk, qk);
  k_transpose_qk<<<dim3(64, 8), 256, 0, stream>>>(qk, q1t, k1t);
  k_sp_stats_mfma<<<dim3(64, 8), 256, 0, stream>>>(q1t, k1t, qk, k1d);
  k_ch_scores<<<dim3(32, 8), 256, 0, stream>>>(qk, part);
  k_ch_softmax<<<512, 64, 0, stream>>>(part, attn2);
  k_ch_apply<<<dim3(64, 8), 256, 0, stream>>>(qk, attn2, cpre);
  k_sp_apply_mfma<<<dim3(64, NSPLIT, 8), 256, 0, stream>>>(q1t, k1t, k1d, spre);
  k_final_mfma<<<dim3(32, 4, 8), 256, 0, stream>>>(spre, cpre, Wfb, bfb, out);
}

// Round 7
// 432.963 us; speedup vs baseline: 1.0015x; 1.0015x over previous
//
#include <hip/hip_runtime.h>

typedef unsigned short u16;
typedef unsigned int   u32;
typedef __attribute__((ext_vector_type(8))) short short8;  // 8 bf16 = one MFMA A/B frag
typedef __attribute__((ext_vector_type(4))) float f32x4;   // MFMA C/D frag

__device__ __forceinline__ u16 f2bf(float f) {
  u32 u = __float_as_uint(f);
  u32 r = u + 0x7fffu + ((u >> 16) & 1u);
  return (u16)(r >> 16);
}

__device__ __forceinline__ void gl_lds16(const u16* g, u16* l) {
  __builtin_amdgcn_global_load_lds(
      (const __attribute__((address_space(1))) u32*)g,
      (__attribute__((address_space(3))) u32*)l, 16, 0, 0);
}

// ---------------------------------------------------------------------------
// Kernel 1: fold q/k projections into the input convs; emit bf16 Wqkb.
// ---------------------------------------------------------------------------
__global__ __launch_bounds__(256) void k_combine_qk(
    const float* __restrict__ wt, const float* __restrict__ bt,
    const float* __restrict__ wb, const float* __restrict__ bb,
    const float* __restrict__ s_w1, const float* __restrict__ s_b1,
    const float* __restrict__ s_w2, const float* __restrict__ s_b2,
    const float* __restrict__ c_wq, const float* __restrict__ c_bq,
    const float* __restrict__ c_wk, const float* __restrict__ c_bk,
    u16* __restrict__ Wqkb, float* __restrict__ bqk) {
  int j = blockIdx.x;            // 0..255
  int g = j >> 6, r = j & 63;
  const float* sw; const float* sb;
  if (g == 0)      { sw = s_w1; sb = s_b1; }
  else if (g == 1) { sw = s_w2; sb = s_b2; }
  else if (g == 2) { sw = c_wq; sb = c_bq; }
  else             { sw = c_wk; sb = c_bk; }
  int cbase = (g < 2) ? 0 : 256;

  __shared__ float swr[256];
  __shared__ float red[256];
  int t = threadIdx.x;
  swr[t] = sw[r * 256 + t];
  __syncthreads();

  float a0 = 0.f, a1 = 0.f, a2 = 0.f, a3 = 0.f;
#pragma unroll 4
  for (int c = 0; c < 256; ++c) {
    float a = swr[c];
    int row = (cbase + c) * 512;
    a0 += a * wt[row + t];
    a1 += a * wt[row + 256 + t];
    a2 += a * wb[row + t];
    a3 += a * wb[row + 256 + t];
  }
  Wqkb[j * 1024 + t]       = f2bf(a0);
  Wqkb[j * 1024 + 256 + t] = f2bf(a1);
  Wqkb[j * 1024 + 512 + t] = f2bf(a2);
  Wqkb[j * 1024 + 768 + t] = f2bf(a3);

  red[t] = swr[t] * (bt[cbase + t] + bb[cbase + t]);
  __syncthreads();
  for (int s = 128; s > 0; s >>= 1) {
    if (t < s) red[t] += red[t + s];
    __syncthreads();
  }
  if (t == 0) bqk[j] = red[0] + sb[r];
}

// ---------------------------------------------------------------------------
// Kernel 2: fold s_wo / c_wo into the final conv; emit bf16 Wfb.
// ---------------------------------------------------------------------------
__global__ __launch_bounds__(128) void k_combine_f(
    const float* __restrict__ f_w, const float* __restrict__ f_b,
    const float* __restrict__ s_wo, const float* __restrict__ s_bo,
    const float* __restrict__ c_wo, const float* __restrict__ c_bo,
    u16* __restrict__ Wfb, float* __restrict__ bfb) {
  int o = blockIdx.x;   // 0..511
  int t = threadIdx.x;  // 0..127
  __shared__ float fwr[512];
  __shared__ float red[128];
  for (int i = t; i < 512; i += 128) fwr[i] = f_w[o * 512 + i];
  __syncthreads();

  float acc = 0.f;
  if (t < 64) {
#pragma unroll 4
    for (int c = 0; c < 256; ++c) acc += fwr[c] * s_wo[c * 64 + t];
  } else {
    int rr = t - 64;
#pragma unroll 4
    for (int c = 0; c < 256; ++c) acc += fwr[256 + c] * c_wo[c * 64 + rr];
  }
  Wfb[o * 128 + t] = f2bf(acc);

  red[t] = fwr[t] * s_bo[t] + fwr[t + 128] * s_bo[t + 128]
         + fwr[256 + t] * c_bo[t] + fwr[384 + t] * c_bo[t + 128];
  __syncthreads();
  for (int s = 64; s > 0; s >>= 1) {
    if (t < s) red[t] += red[t + s];
    __syncthreads();
  }
  if (t == 0) bfb[o] = red[0] + f_b[o];
}

// ---------------------------------------------------------------------------
// Kernel 3 (MFMA, v7): qk[b][j][n] = sum_k Wqk[j][k]*x[b][k][n] + bqk[j]
// v7 = EXACT v5 pipeline/X-path (best measured; v6's float4-X write pattern
// collapsed the bank spread -> reverted) + FUSED T1: blockIdx.y==0 blocks
// hold complete q1 (j 0..63) / k1 (j 64..127) rows for their n-slice, so the
// epilogue also emits the bf16 channel-minor q1t/k1t copies directly from
// acc+bias (bit-identical to old T1's f2bf(qk[...]) since qk stores exact
// fp32). k_transpose_qk is deleted.
// LDS = 2*8KB(A) + 2*8KB(X) = 32 KB.
// ---------------------------------------------------------------------------
__global__ __launch_bounds__(256) void k_gemm_qk_mfma(
    const float* __restrict__ top, const float* __restrict__ bot,
    const u16* __restrict__ Wqkb, const float* __restrict__ bqk,
    float* __restrict__ qk, u16* __restrict__ q1t, u16* __restrict__ k1t) {
  int b = blockIdx.z, j0 = blockIdx.y * 128, n0 = blockIdx.x * 128;
  __shared__ __align__(16) u16 Aj[2][128][32];
  __shared__ __align__(16) u16 Xs[2][128][32];
  int t = threadIdx.x;
  int wv = t >> 6, lane = t & 63;
  int wr = wv >> 1, wc = wv & 1;
  int q = lane >> 4, l = lane & 15;

  f32x4 acc[4][4];
#pragma unroll
  for (int tr = 0; tr < 4; ++tr)
#pragma unroll
    for (int tc = 0; tc < 4; ++tc) acc[tr][tc] = (f32x4){0.f, 0.f, 0.f, 0.f};

  // ---- X staging mapping: thread owns (n = xn+32p, u16 k in [4xs,4xs+3]) ---
  int xn = t & 31;
  int xs = t >> 5;                               // 0..7
  int kx = (xn + (xn >> 2)) & 3;                 // swizzle key of row xn (+32p inv.)
  int wcol = ((((xs >> 1) ^ kx) << 4) | ((xs & 1) << 3));  // byte col in 64B row
  // ---- A staging (gl_lds, lane-linear dest): per-lane swizzled source -----
  int asr4 = lane >> 2;                          // row within 16-row chunk
  int asc = (lane & 3) ^ ((asr4 + (asr4 >> 2)) & 3);  // logical 16B chunk to fetch
  // ---- fragment-read swizzled chunk offsets (per-thread constants) --------
  int rowA = wr * 64 + l;
  int rowX = wc * 64 + l;
  int fswA = (q ^ ((rowA + (rowA >> 2)) & 3)) << 4;
  int fswX = (q ^ ((rowX + (rowX >> 2)) & 3)) << 4;

  float xva[16], xvb[16];

  auto stageA = [&](int kc, u16* dst) {
#pragma unroll
    for (int pp = 0; pp < 2; ++pp) {
      int p = wv * 2 + pp;                       // 1KB chunk 0..7
      int row = p * 16 + asr4;                   // 0..127
      gl_lds16(Wqkb + (size_t)(j0 + row) * 1024 + kc + asc * 8, dst + p * 512);
    }
  };
  auto loadX = [&](int kc, float (&xv)[16]) {
    const float* src = (kc < 512) ? top : bot;
    int c0 = kc & 511;
    const float* xb = src + (size_t)(b * 512 + c0) * 4096 + n0;
#pragma unroll
    for (int p = 0; p < 4; ++p) {
      int n = xn + 32 * p;
#pragma unroll
      for (int d = 0; d < 4; ++d)
        xv[4 * p + d] = xb[(size_t)(4 * xs + d) * 4096 + n];
    }
  };
  auto writeX = [&](float (&xv)[16], u16* dst) {
    char* base = reinterpret_cast<char*>(dst);
#pragma unroll
    for (int p = 0; p < 4; ++p) {
      int n = xn + 32 * p;
      uint2 pk;
      pk.x = (u32)f2bf(xv[4 * p])     | ((u32)f2bf(xv[4 * p + 1]) << 16);
      pk.y = (u32)f2bf(xv[4 * p + 2]) | ((u32)f2bf(xv[4 * p + 3]) << 16);
      *reinterpret_cast<uint2*>(base + n * 64 + wcol) = pk;
    }
  };
  auto compute = [&](int bufsel) {
    const char* Ab = reinterpret_cast<const char*>(&Aj[bufsel][0][0]);
    const char* Xb = reinterpret_cast<const char*>(&Xs[bufsel][0][0]);
    short8 af[4], bfr[4];
#pragma unroll
    for (int tr = 0; tr < 4; ++tr)
      af[tr] = *reinterpret_cast<const short8*>(Ab + (rowA + tr * 16) * 64 + fswA);
#pragma unroll
    for (int tc = 0; tc < 4; ++tc)
      bfr[tc] = *reinterpret_cast<const short8*>(Xb + (rowX + tc * 16) * 64 + fswX);
#pragma unroll
    for (int tr = 0; tr < 4; ++tr)
#pragma unroll
      for (int tc = 0; tc < 4; ++tc)
        acc[tr][tc] = __builtin_amdgcn_mfma_f32_16x16x32_bf16(
            af[tr], bfr[tc], acc[tr][tc], 0, 0, 0);
  };

  // ---- prologue: tile 0 resident; tile 1 X-data in flight -----------------
  stageA(0, &Aj[0][0][0]);
  loadX(0, xva);
  writeX(xva, &Xs[0][0][0]);     // register deps drain vmcnt (A0 done too)
  loadX(32, xvb);                // 16 in flight across the barrier
  asm volatile("s_waitcnt lgkmcnt(0)" ::: "memory");
  __builtin_amdgcn_s_barrier();

  // ---- main loop: phases 0..29 (two per trip) -----------------------------
  for (int it2 = 0; it2 < 15; ++it2) {
    int e = it2 * 2;
    // phase e (buf 0): prep tile e+1 in buf1, load tile e+2
    stageA((e + 1) * 32, &Aj[1][0][0]);
    loadX((e + 2) * 32, xva);
    writeX(xvb, &Xs[1][0][0]);   // waits tile-(e+1) loads (aged 1 phase)
    compute(0);
    asm volatile("s_waitcnt vmcnt(16) lgkmcnt(0)" ::: "memory");
    __builtin_amdgcn_s_barrier();
    // phase e+1 (buf 1): prep tile e+2 in buf0, load tile e+3
    stageA((e + 2) * 32, &Aj[0][0][0]);
    loadX((e + 3) * 32, xvb);
    writeX(xva, &Xs[0][0][0]);
    compute(1);
    asm volatile("s_waitcnt vmcnt(16) lgkmcnt(0)" ::: "memory");
    __builtin_amdgcn_s_barrier();
  }
  // ---- peel: phase 30 (prepare tile 31), phase 31 -------------------------
  stageA(31 * 32, &Aj[1][0][0]);
  writeX(xvb, &Xs[1][0][0]);     // xvb: tile 31 (loaded phase 29)
  compute(0);
  asm volatile("s_waitcnt vmcnt(0) lgkmcnt(0)" ::: "memory");
  __builtin_amdgcn_s_barrier();
  compute(1);

  // ---- epilogue: fp32 qk + (y==0) fused bf16 q1t/k1t ----------------------
  bool doT = (j0 == 0);
  u16* tdst = (wr == 0) ? q1t : k1t;   // j_local<64 -> q1, else k1
#pragma unroll
  for (int tr = 0; tr < 4; ++tr) {
    int jl = wr * 64 + tr * 16 + q * 4;          // 0..127
    int j = j0 + jl;
    int jc = jl & 63;
    float4 bias = *reinterpret_cast<const float4*>(&bqk[j]);
#pragma unroll
    for (int tc = 0; tc < 4; ++tc) {
      int n = n0 + wc * 64 + tc * 16 + l;
      float v0 = acc[tr][tc][0] + bias.x;
      float v1 = acc[tr][tc][1] + bias.y;
      float v2 = acc[tr][tc][2] + bias.z;
      float v3 = acc[tr][tc][3] + bias.w;
      float* dst = qk + (size_t)(b * 256 + j) * 4096 + n;
      dst[0]        = v0;
      dst[4096]     = v1;
      dst[2 * 4096] = v2;
      dst[3 * 4096] = v3;
      if (doT) {
        uint2 pk;
        pk.x = (u32)f2bf(v0) | ((u32)f2bf(v1) << 16);
        pk.y = (u32)f2bf(v2) | ((u32)f2bf(v3) << 16);
        *reinterpret_cast<uint2*>(tdst + ((size_t)(b * 4096) + n) * 64 + jc) = pk;
      }
    }
  }
}

// ---------------------------------------------------------------------------
// Kernel 4 (MFMA, v2): spatial softmax denominators + fused k1d scaling.
// ---------------------------------------------------------------------------
__global__ __launch_bounds__(256) void k_sp_stats_mfma(
    const u16* __restrict__ q1t, const u16* __restrict__ k1t,
    const float* __restrict__ qk, u16* __restrict__ k1d) {
  int b = blockIdx.y, n0 = blockIdx.x * 64;
  __shared__ u16 Qs[64][72];
  __shared__ float red[4][64][16];
  __shared__ float dvs[64];
  int t = threadIdx.x;
  int wv = t >> 6, lane = t & 63;
  int q = lane >> 4, l = lane & 15;

  {
    const u32* src = reinterpret_cast<const u32*>(q1t + ((size_t)(b * 4096) + n0) * 64);
    for (int i = t; i < 2048; i += 256) {
      int n = i >> 5, c = i & 31;
      reinterpret_cast<u32*>(&Qs[n][0])[c] = src[n * 32 + c];
    }
  }
  __syncthreads();

  short8 afr[4][2];
#pragma unroll
  for (int tn = 0; tn < 4; ++tn)
#pragma unroll
    for (int kh = 0; kh < 2; ++kh)
      afr[tn][kh] = *reinterpret_cast<const short8*>(&Qs[tn * 16 + l][kh * 32 + q * 8]);

  const u16* kbase = k1t + (size_t)b * 4096 * 64;
  float dsum[4][4];
#pragma unroll
  for (int tn = 0; tn < 4; ++tn)
#pragma unroll
    for (int i = 0; i < 4; ++i) dsum[tn][i] = 0.f;

  for (int mt = wv; mt < 64; mt += 4) {
    int m0 = mt * 64;
#pragma unroll
    for (int tm = 0; tm < 4; ++tm) {
      const u16* kp = kbase + ((size_t)(m0 + tm * 16 + l)) * 64;
      short8 b0 = *reinterpret_cast<const short8*>(kp + q * 8);
      short8 b1 = *reinterpret_cast<const short8*>(kp + 32 + q * 8);
#pragma unroll
      for (int tn = 0; tn < 4; ++tn) {
        f32x4 acc = {0.f, 0.f, 0.f, 0.f};
        acc = __builtin_amdgcn_mfma_f32_16x16x32_bf16(afr[tn][0], b0, acc, 0, 0, 0);
        acc = __builtin_amdgcn_mfma_f32_16x16x32_bf16(afr[tn][1], b1, acc, 0, 0, 0);
#pragma unroll
        for (int i = 0; i < 4; ++i) dsum[tn][i] += __expf(acc[i]);
      }
    }
  }

#pragma unroll
  for (int tn = 0; tn < 4; ++tn)
#pragma unroll
    for (int i = 0; i < 4; ++i)
      red[wv][tn * 16 + q * 4 + i][l] = dsum[tn][i];
  __syncthreads();
  if (t < 64) {
    float s = 0.f;
#pragma unroll
    for (int v = 0; v < 4; ++v)
#pragma unroll
      for (int u = 0; u < 16; ++u) s += red[v][t][u];
    dvs[t] = 1.0f / s;
  }
  __syncthreads();

  // fused: k1d for this n-slice (identical numerics to old k_scale_k1d)
  const float* k1src = qk + ((size_t)(b * 256) + 64) * 4096 + n0;
  u16* kdst = k1d + (size_t)(b * 64) * 4096 + n0;
  for (int i = t; i < 4096; i += 256) {
    int r = i >> 6, n = i & 63;
    kdst[(size_t)r * 4096 + n] = f2bf(k1src[(size_t)r * 4096 + n] * dvs[n]);
  }
}

// ---------------------------------------------------------------------------
// Kernel 8 (MFMA, v2): spatial apply. (unchanged)
// ---------------------------------------------------------------------------
#define NSPLIT 2

__device__ __forceinline__ void stage_qk(const u16* qb, const u16* kb, int noff,
                                         u16* qdst, u16* kdst,
                                         int wv, int rsub, int scol) {
#pragma unroll
  for (int pp = 0; pp < 2; ++pp) {
    int p = wv * 2 + pp;                 // 1KB chunk index 0..7 (2 per wave)
    int row = p * 8 + rsub;              // tile row 0..63
    gl_lds16(qb + ((size_t)(noff + row)) * 64 + scol * 8, qdst + p * 512);
    gl_lds16(kb + (size_t)row * 4096 + noff + scol * 8, kdst + p * 512);
  }
}

__global__ __launch_bounds__(256) void k_sp_apply_mfma(
    const u16* __restrict__ q1t, const u16* __restrict__ k1t,
    const u16* __restrict__ k1d, float* __restrict__ spre) {
  int b = blockIdx.z, m0 = blockIdx.x * 64;
  int n_base = blockIdx.y * (4096 / NSPLIT);
  const int NT = 64 / NSPLIT;

  __shared__ __align__(16) u16 Qs[2][64][64];
  __shared__ __align__(16) u16 Ks[2][64][64];
  __shared__ __align__(16) u16 Wt[64][64];

  int t = threadIdx.x;
  int wv = t >> 6, lane = t & 63;
  int q = lane >> 4, l = lane & 15;
  int sw = l & 7;                        // swizzle key: row&7 == l&7 for frag rows
  int rsub = lane >> 3;                  // staging: row within 8-row chunk
  int scol = (lane & 7) ^ rsub;          // staging: pre-swizzled source 16B-chunk

  // B fragments (K^T tile at m0): straight global->reg, live whole kernel.
  const u16* ktp = k1t + ((size_t)(b * 4096) + m0 + wv * 16 + l) * 64;
  short8 bS0 = *reinterpret_cast<const short8*>(ktp + q * 8);
  short8 bS1 = *reinterpret_cast<const short8*>(ktp + 32 + q * 8);

  const u16* qb = q1t + (size_t)b * 4096 * 64;
  const u16* kb = k1d + (size_t)b * 64 * 4096;

  f32x4 accO[4];
#pragma unroll
  for (int tr = 0; tr < 4; ++tr) accO[tr] = (f32x4){0.f, 0.f, 0.f, 0.f};

  stage_qk(qb, kb, n_base, &Qs[0][0][0], &Ks[0][0][0], wv, rsub, scol);
  __syncthreads();   // vmcnt(0) drain: buf0 ready

  int wrow = wv * 16 + l;
  char* wp = reinterpret_cast<char*>(&Wt[wrow][0]);
  int c_a0 = (q ^ sw) << 4;              // swizzled byte offset of chunk q
  int c_a1 = c_a0 ^ 64;                  // chunk q+4

  int cur = 0;
  for (int nt = 0; nt < NT; ++nt) {
    if (nt + 1 < NT)
      stage_qk(qb, kb, n_base + (nt + 1) * 64,
               &Qs[cur ^ 1][0][0], &Ks[cur ^ 1][0][0], wv, rsub, scol);

    const u16(*Qc)[64] = Qs[cur];
    const u16(*Kc)[64] = Ks[cur];

    // scores tile: W[n][m] = exp(q1[n] . k1[m]) ; wave-private Wt round-trip
#pragma unroll
    for (int tn = 0; tn < 4; ++tn) {
      const char* qrow = reinterpret_cast<const char*>(&Qc[tn * 16 + l][0]);
      short8 a0 = *reinterpret_cast<const short8*>(qrow + c_a0);
      short8 a1 = *reinterpret_cast<const short8*>(qrow + c_a1);
      f32x4 s = {0.f, 0.f, 0.f, 0.f};
      s = __builtin_amdgcn_mfma_f32_16x16x32_bf16(a0, bS0, s, 0, 0, 0);
      s = __builtin_amdgcn_mfma_f32_16x16x32_bf16(a1, bS1, s, 0, 0, 0);
      u16 w0 = f2bf(__expf(s[0]));
      u16 w1 = f2bf(__expf(s[1]));
      u16 w2 = f2bf(__expf(s[2]));
      u16 w3 = f2bf(__expf(s[3]));
      uint2 pk;
      pk.x = (u32)w0 | ((u32)w1 << 16);
      pk.y = (u32)w2 | ((u32)w3 << 16);
      *reinterpret_cast<uint2*>(
          wp + ((((tn * 2 + (q >> 1)) ^ sw) << 4) | ((q & 1) << 3))) = pk;
    }

    short8 bW0 = *reinterpret_cast<const short8*>(wp + c_a0);
    short8 bW1 = *reinterpret_cast<const short8*>(wp + c_a1);
#pragma unroll
    for (int tr = 0; tr < 4; ++tr) {
      const char* krow = reinterpret_cast<const char*>(&Kc[tr * 16 + l][0]);
      short8 a0 = *reinterpret_cast<const short8*>(krow + c_a0);
      short8 a1 = *reinterpret_cast<const short8*>(krow + c_a1);
      accO[tr] = __builtin_amdgcn_mfma_f32_16x16x32_bf16(a0, bW0, accO[tr], 0, 0, 0);
      accO[tr] = __builtin_amdgcn_mfma_f32_16x16x32_bf16(a1, bW1, accO[tr], 0, 0, 0);
    }

    __syncthreads();   // drains vmcnt (next buf ready) + lgkmcnt (cur reads done)
    cur ^= 1;
  }

#pragma unroll
  for (int tr = 0; tr < 4; ++tr)
#pragma unroll
    for (int i = 0; i < 4; ++i)
      atomicAdd(&spre[(size_t)(b * 64 + tr * 16 + q * 4 + i) * 4096 + m0 + wrow],
                accO[tr][i]);
}

// ---------------------------------------------------------------------------
// Kernel 5 (v2): channel attention partial scores. 32 n-chunks -> 256 blocks.
// ---------------------------------------------------------------------------
__global__ __launch_bounds__(256) void k_ch_scores(
    const float* __restrict__ qk, float* __restrict__ part) {
  int b = blockIdx.y, ch = blockIdx.x;   // ch 0..31, chunk of 128 n
  const float* q2 = qk + (size_t)(b * 256 + 128) * 4096;
  const float* k2 = qk + (size_t)(b * 256 + 192) * 4096;
  __shared__ float Qs[64][65];
  __shared__ float Ks[64][65];
  int t = threadIdx.x, ti = t >> 4, tj = t & 15;
  float acc[4][4] = {};

  for (int sub = 0; sub < 2; ++sub) {
    int n0 = ch * 128 + sub * 64;
    __syncthreads();
    for (int i = t; i < 4096; i += 256) {
      int r = i >> 6, n = i & 63;
      Qs[r][n] = q2[(size_t)r * 4096 + n0 + n];
      Ks[r][n] = k2[(size_t)r * 4096 + n0 + n];
    }
    __syncthreads();
#pragma unroll
    for (int n = 0; n < 64; ++n) {
      float qa[4], ka[4];
#pragma unroll
      for (int i = 0; i < 4; ++i) qa[i] = Qs[ti * 4 + i][n];
#pragma unroll
      for (int jx = 0; jx < 4; ++jx) ka[jx] = Ks[tj * 4 + jx][n];
#pragma unroll
      for (int i = 0; i < 4; ++i)
#pragma unroll
        for (int jx = 0; jx < 4; ++jx) acc[i][jx] += qa[i] * ka[jx];
    }
  }
#pragma unroll
  for (int i = 0; i < 4; ++i)
#pragma unroll
    for (int jx = 0; jx < 4; ++jx)
      part[(size_t)(b * 32 + ch) * 4096 + (ti * 4 + i) * 64 + tj * 4 + jx] = acc[i][jx];
}

// ---------------------------------------------------------------------------
// Kernel 6 (v2): reduce 32 partials + row softmax -> attn2[b][r][s]
// ---------------------------------------------------------------------------
__global__ __launch_bounds__(64) void k_ch_softmax(
    const float* __restrict__ part, float* __restrict__ attn2) {
  int bid = blockIdx.x;          // 512 = 8 b * 64 r
  int b = bid >> 6, r = bid & 63;
  int s = threadIdx.x;
  const float* p0 = part + (size_t)(b * 32) * 4096 + r * 64 + s;
  float sum = 0.f;
#pragma unroll
  for (int c = 0; c < 32; ++c) sum += p0[(size_t)c * 4096];
  float mx = sum;
#pragma unroll
  for (int o = 32; o > 0; o >>= 1) mx = fmaxf(mx, __shfl_xor(mx, o));
  float e = __expf(sum - mx);
  float den = e;
#pragma unroll
  for (int o = 32; o > 0; o >>= 1) den += __shfl_xor(den, o);
  attn2[(size_t)b * 4096 + r * 64 + s] = e / den;
}

// ---------------------------------------------------------------------------
// Kernel 7 (v2): cpre[b][r][n] = sum_s attn2[r,s] * k2[s,n]
// ---------------------------------------------------------------------------
__global__ __launch_bounds__(256) void k_ch_apply(
    const float* __restrict__ qk, const float* __restrict__ attn2,
    float* __restrict__ cpre) {
  int b = blockIdx.y;
  int t = threadIdx.x;
  int n = blockIdx.x * 64 + (t & 63);
  int qr = t >> 6;                      // r-quarter 0..3
  const float* k2 = qk + (size_t)(b * 256 + 192) * 4096;
  __shared__ float As[64][64];
  {
    float4* As4 = reinterpret_cast<float4*>(&As[0][0]);
    const float4* a4 = reinterpret_cast<const float4*>(attn2 + (size_t)b * 4096);
    for (int i = t; i < 1024; i += 256) As4[i] = a4[i];
  }
  __syncthreads();

  float acc[16];
#pragma unroll
  for (int rr = 0; rr < 16; ++rr) acc[rr] = 0.f;
  for (int s4 = 0; s4 < 64; s4 += 4) {
    float kv0 = k2[(size_t)(s4 + 0) * 4096 + n];
    float kv1 = k2[(size_t)(s4 + 1) * 4096 + n];
    float kv2 = k2[(size_t)(s4 + 2) * 4096 + n];
    float kv3 = k2[(size_t)(s4 + 3) * 4096 + n];
#pragma unroll
    for (int rr = 0; rr < 16; ++rr) {
      float4 w = *reinterpret_cast<const float4*>(&As[qr * 16 + rr][s4]);
      acc[rr] += w.x * kv0 + w.y * kv1 + w.z * kv2 + w.w * kv3;
    }
  }
#pragma unroll
  for (int rr = 0; rr < 16; ++rr)
    cpre[(size_t)(b * 64 + qr * 16 + rr) * 4096 + n] = acc[rr];
}

// ---------------------------------------------------------------------------
// Kernel 9 (MFMA, v2): final fused conv, counted-vmcnt template. (unchanged)
// ---------------------------------------------------------------------------
__global__ __launch_bounds__(256) void k_final_mfma(
    const float* __restrict__ spre, const float* __restrict__ cpre,
    const u16* __restrict__ Wfb, const float* __restrict__ bfb,
    float* __restrict__ out) {
  int b = blockIdx.z, o0 = blockIdx.y * 128, n0 = blockIdx.x * 128;
  __shared__ __align__(16) u16 Aj[2][128][32];
  __shared__ __align__(16) u16 Xs[2][128][32];
  int t = threadIdx.x;
  int wv = t >> 6, lane = t & 63;
  int wr = wv >> 1, wc = wv & 1;
  int q = lane >> 4, l = lane & 15;

  f32x4 acc[4][4];
#pragma unroll
  for (int tr = 0; tr < 4; ++tr)
#pragma unroll
    for (int tc = 0; tc < 4; ++tc) acc[tr][tc] = (f32x4){0.f, 0.f, 0.f, 0.f};

  int a = t & 31;
  int xs = t >> 5;
  int asr4 = lane >> 2;
  int asc = (lane & 3) ^ ((asr4 + (asr4 >> 2)) & 3);
  int rowA = wr * 64 + l;
  int rowX = wc * 64 + l;
  int fswA = (q ^ ((rowA + (rowA >> 2)) & 3)) << 4;
  int fswX = (q ^ ((rowX + (rowX >> 2)) & 3)) << 4;

  f32x4 xva[4], xvb[4];

  auto stageA = [&](int kc, u16* dst) {
#pragma unroll
    for (int pp = 0; pp < 2; ++pp) {
      int p = wv * 2 + pp;
      int row = p * 16 + asr4;
      gl_lds16(Wfb + (size_t)(o0 + row) * 128 + kc + asc * 8, dst + p * 512);
    }
  };
  auto loadX = [&](int kc, f32x4 (&xv)[4]) {
    const float* src = (kc < 64) ? spre : cpre;
    int r0 = kc & 63;
    const float* xb = src + (size_t)(b * 64 + r0) * 4096 + n0 + 4 * a;
#pragma unroll
    for (int d = 0; d < 4; ++d)
      xv[d] = *reinterpret_cast<const f32x4*>(&xb[(size_t)(4 * xs + d) * 4096]);
  };
  auto writeX = [&](f32x4 (&xv)[4], u16* dst) {
    char* base = reinterpret_cast<char*>(dst);
#pragma unroll
    for (int i = 0; i < 4; ++i) {
      int n = 4 * a + i;
      int key = (n + (n >> 2)) & 3;
      int col = ((((xs >> 1) ^ key) << 4) | ((xs & 1) << 3));
      uint2 pk;
      pk.x = (u32)f2bf(xv[0][i]) | ((u32)f2bf(xv[1][i]) << 16);
      pk.y = (u32)f2bf(xv[2][i]) | ((u32)f2bf(xv[3][i]) << 16);
      *reinterpret_cast<uint2*>(base + n * 64 + col) = pk;
    }
  };
  auto compute = [&](int bufsel) {
    const char* Ab = reinterpret_cast<const char*>(&Aj[bufsel][0][0]);
    const char* Xb = reinterpret_cast<const char*>(&Xs[bufsel][0][0]);
    short8 af[4], bfr[4];
#pragma unroll
    for (int tr = 0; tr < 4; ++tr)
      af[tr] = *reinterpret_cast<const short8*>(Ab + (rowA + tr * 16) * 64 + fswA);
#pragma unroll
    for (int tc = 0; tc < 4; ++tc)
      bfr[tc] = *reinterpret_cast<const short8*>(Xb + (rowX + tc * 16) * 64 + fswX);
#pragma unroll
    for (int tr = 0; tr < 4; ++tr)
#pragma unroll
      for (int tc = 0; tc < 4; ++tc)
        acc[tr][tc] = __builtin_amdgcn_mfma_f32_16x16x32_bf16(
            af[tr], bfr[tc], acc[tr][tc], 0, 0, 0);
  };

  // prologue: tile0 resident, tile1 in flight
  stageA(0, &Aj[0][0][0]);
  loadX(0, xva);
  writeX(xva, &Xs[0][0][0]);
  loadX(32, xvb);
  asm volatile("s_waitcnt lgkmcnt(0)" ::: "memory");
  __builtin_amdgcn_s_barrier();
  // phase 0: compute tile0; prep tile1; load tile2
  stageA(32, &Aj[1][0][0]);
  loadX(64, xva);
  writeX(xvb, &Xs[1][0][0]);
  compute(0);
  asm volatile("s_waitcnt vmcnt(4) lgkmcnt(0)" ::: "memory");
  __builtin_amdgcn_s_barrier();
  // phase 1: compute tile1; prep tile2; load tile3
  stageA(64, &Aj[0][0][0]);
  loadX(96, xvb);
  writeX(xva, &Xs[0][0][0]);
  compute(1);
  asm volatile("s_waitcnt vmcnt(4) lgkmcnt(0)" ::: "memory");
  __builtin_amdgcn_s_barrier();
  // phase 2: compute tile2; prep tile3
  stageA(96, &Aj[1][0][0]);
  writeX(xvb, &Xs[1][0][0]);
  compute(0);
  asm volatile("s_waitcnt vmcnt(0) lgkmcnt(0)" ::: "memory");
  __builtin_amdgcn_s_barrier();
  // phase 3
  compute(1);

#pragma unroll
  for (int tr = 0; tr < 4; ++tr) {
    int o = o0 + wr * 64 + tr * 16 + q * 4;
    float4 bias = *reinterpret_cast<const float4*>(&bfb[o]);
#pragma unroll
    for (int tc = 0; tc < 4; ++tc) {
      int n = n0 + wc * 64 + tc * 16 + l;
      float* dst = out + (size_t)(b * 512 + o) * 4096 + n;
      dst[0]        = acc[tr][tc][0] + bias.x;
      dst[4096]     = acc[tr][tc][1] + bias.y;
      dst[2 * 4096] = acc[tr][tc][2] + bias.z;
      dst[3 * 4096] = acc[tr][tc][3] + bias.w;
    }
  }
}

// ---------------------------------------------------------------------------
extern "C" void kernel_launch(void* const* d_in, const int* in_sizes, int n_in,
                              void* d_out, int out_size, void* d_ws, size_t ws_size,
                              hipStream_t stream) {
  const float* top  = (const float*)d_in[0];
  const float* bot  = (const float*)d_in[1];
  const float* wt   = (const float*)d_in[2];
  const float* bt   = (const float*)d_in[3];
  const float* wb   = (const float*)d_in[4];
  const float* bb   = (const float*)d_in[5];
  const float* s_w1 = (const float*)d_in[6];
  const float* s_b1 = (const float*)d_in[7];
  const float* s_w2 = (const float*)d_in[8];
  const float* s_b2 = (const float*)d_in[9];
  const float* s_wo = (const float*)d_in[10];
  const float* s_bo = (const float*)d_in[11];
  const float* c_wq = (const float*)d_in[12];
  const float* c_bq = (const float*)d_in[13];
  const float* c_wk = (const float*)d_in[14];
  const float* c_bk = (const float*)d_in[15];
  const float* c_wo = (const float*)d_in[16];
  const float* c_bo = (const float*)d_in[17];
  const float* f_w  = (const float*)d_in[18];
  const float* f_b  = (const float*)d_in[19];
  float* out = (float*)d_out;

  // d_out (64 MB) doubles as scratch until k_final_mfma overwrites it:
  //   [0,32MB)  qk fp32 [8][256][4096]
  //   [32,36MB) q1t bf16 [8][4096][64]   (written by fused gemm epilogue)
  //   [36,40MB) k1t bf16 [8][4096][64]   (written by fused gemm epilogue)
  //   [40,44MB) k1d bf16 [8][64][4096]
  //   [44,48MB) part fp32 [8][32][64][64]   (consumed by k_ch_softmax)
  char* ob = (char*)d_out;
  float* qk = (float*)ob;
  u16* q1t = (u16*)(ob + 33554432);
  u16* k1t = (u16*)(ob + 37748736);
  u16* k1d = (u16*)(ob + 41943040);
  float* part = (float*)(ob + 46137344);

  char* ws = (char*)d_ws;
  float* attn2 = (float*)(ws + 1179648);    // [8][64][64]        131,072 B
  float* spre  = (float*)(ws + 1310720);    // [8][64][4096]    8,388,608 B
  float* cpre  = (float*)(ws + 9699328);    // [8][64][4096]    8,388,608 B
  u16*   Wqkb  = (u16*)  (ws + 18087936);   // [256][1024] bf16   524,288 B
  float* bqk   = (float*)(ws + 18612224);   // [256]                1,024 B
  u16*   Wfb   = (u16*)  (ws + 18613248);   // [512][128] bf16    131,072 B
  float* bfb   = (float*)(ws + 18744320);   // [512]                2,048 B

  // spre is accumulated with atomicAdd by the NSPLIT partial blocks -> zero it.
  hipMemsetAsync(spre, 0, 8388608, stream);

  k_combine_qk<<<256, 256, 0, stream>>>(wt, bt, wb, bb, s_w1, s_b1, s_w2, s_b2,
                                        c_wq, c_bq, c_wk, c_bk, Wqkb, bqk);
  k_combine_f<<<512, 128, 0, stream>>>(f_w, f_b, s_wo, s_bo, c_wo, c_bo, Wfb, bfb);
  k_gemm_qk_mfma<<<dim3(32, 2, 8), 256, 0, stream>>>(top, bot, Wqkb, bqk, qk,
                                                     q1t, k1t);
  k_sp_stats_mfma<<<dim3(64, 8), 256, 0, stream>>>(q1t, k1t, qk, k1d);
  k_ch_scores<<<dim3(32, 8), 256, 0, stream>>>(qk, part);
  k_ch_softmax<<<512, 64, 0, stream>>>(part, attn2);
  k_ch_apply<<<dim3(64, 8), 256, 0, stream>>>(qk, attn2, cpre);
  k_sp_apply_mfma<<<dim3(64, NSPLIT, 8), 256, 0, stream>>>(q1t, k1t, k1d, spre);
  k_final_mfma<<<dim3(32, 4, 8), 256, 0, stream>>>(spre, cpre, Wfb, bfb, out);
}